// Round 4
// baseline (60.887 us; speedup 1.0000x reference)
//
#include <hip/hip_runtime.h>

#define NN   2048
#define EE   65536
#define EDIM 64
#define LL   5

// Kernel 1: dots[e][l] = sum_d edge_attr[e][d] * edge_vector[l][d]
// 4 edges per wave: lane = (e_sub[2b], dgroup[4b]); float4 over d;
// 4 shuffle levels within 16-lane groups.
__global__ __launch_bounds__(256) void dots_kernel(
    const float* __restrict__ edge_attr,
    const float* __restrict__ edge_vector,
    float* __restrict__ dots) {
  const int lane = threadIdx.x & 63;
  const int wib  = threadIdx.x >> 6;   // wave in block: 0..3
  const int dg   = lane & 15;          // d-group: 4 floats each
  const int es   = lane >> 4;          // edge within wave: 0..3
  const int e    = blockIdx.x * 16 + wib * 4 + es;

  const float4 a = *(const float4*)(edge_attr + e * EDIM + dg * 4);
  float d[LL];
#pragma unroll
  for (int l = 0; l < LL; ++l) {
    const float4 ev = *(const float4*)(edge_vector + l * EDIM + dg * 4);
    d[l] = a.x * ev.x + a.y * ev.y + a.z * ev.z + a.w * ev.w;
  }
#pragma unroll
  for (int s = 1; s <= 8; s <<= 1) {
#pragma unroll
    for (int l = 0; l < LL; ++l) d[l] += __shfl_xor(d[l], s, 64);
  }
  if (dg == 0) {
#pragma unroll
    for (int l = 0; l < LL; ++l) dots[e * LL + l] = d[l];
  }
}

// Kernel 2: 4 (i,j) pairs per thread. Gathers go through a hardware
// bounds-checked buffer SRD: invalid slots use voffset=0x80000000 -> OOB ->
// HW returns 0.0 with no cache access (hypothesis under test). The 0.0
// return kills the whole mask/select chain: s = plain sum of 5 loads,
// and cnt==0 => s==0 => s/(0+1e-10)==0.
__global__ __launch_bounds__(256) void pairs_kernel(
    const int* __restrict__ ept,
    const float* __restrict__ dots,
    float* __restrict__ out) {
  const long t = (long)blockIdx.x * blockDim.x + threadIdx.x;  // 0 .. N*N/4-1

  const int4* p = (const int4*)(ept + t * 20);
  int buf[20];
#pragma unroll
  for (int k = 0; k < 5; ++k) {
    const int4 v = p[k];
    buf[4 * k + 0] = v.x;
    buf[4 * k + 1] = v.y;
    buf[4 * k + 2] = v.z;
    buf[4 * k + 3] = v.w;
  }

  float vals[20];
#if __has_builtin(__builtin_amdgcn_make_buffer_rsrc) && __has_builtin(__builtin_amdgcn_raw_buffer_load_b32)
  const __amdgpu_buffer_rsrc_t rs = __builtin_amdgcn_make_buffer_rsrc(
      (void*)dots, (short)0, EE * LL * 4, 0x00020000);
#pragma unroll
  for (int q = 0; q < 20; ++q) {
    const int id = buf[q];
    const unsigned off =
        (id < 0) ? 0x80000000u : (unsigned)(id * (LL * 4) + (q % LL) * 4);
    const unsigned u = __builtin_amdgcn_raw_buffer_load_b32(rs, (int)off, 0, 0);
    vals[q] = __uint_as_float(u);
  }
#else
#pragma unroll
  for (int q = 0; q < 20; ++q) {
    const int id   = buf[q];
    const int safe = (id < 0) ? 0 : id;
    vals[q] = (id < 0) ? 0.f : dots[safe * LL + (q % LL)];
  }
#endif
  // Keep all 20 results simultaneously live -> one waitcnt batch.
  asm volatile("" : "+v"(vals[0]), "+v"(vals[1]), "+v"(vals[2]), "+v"(vals[3]),
                    "+v"(vals[4]), "+v"(vals[5]), "+v"(vals[6]), "+v"(vals[7]),
                    "+v"(vals[8]), "+v"(vals[9]), "+v"(vals[10]), "+v"(vals[11]),
                    "+v"(vals[12]), "+v"(vals[13]), "+v"(vals[14]), "+v"(vals[15]),
                    "+v"(vals[16]), "+v"(vals[17]), "+v"(vals[18]), "+v"(vals[19]));

  float rr[4];
#pragma unroll
  for (int k = 0; k < 4; ++k) {
    float s = 0.f;
    int cnt = 0;
#pragma unroll
    for (int l = 0; l < LL; ++l) {
      s   += vals[k * LL + l];          // OOB lanes contributed 0.0
      cnt += (buf[k * LL + l] >= 0);
    }
    rr[k] = s / ((float)cnt + 1e-10f);  // cnt==0 -> s==0 -> 0
  }
  *(float4*)(out + t * 4) = make_float4(rr[0], rr[1], rr[2], rr[3]);
}

extern "C" void kernel_launch(void* const* d_in, const int* in_sizes, int n_in,
                              void* d_out, int out_size, void* d_ws, size_t ws_size,
                              hipStream_t stream) {
  // d_in order: x(unused), edge_attr, edge_vector, edge_paths_tensor, edge_paths_length(unused)
  const float* edge_attr   = (const float*)d_in[1];
  const float* edge_vector = (const float*)d_in[2];
  const int*   ept         = (const int*)d_in[3];
  float* out  = (float*)d_out;
  float* dots = (float*)d_ws;  // E * L * 4 = 1.31 MB scratch

  // Kernel 1: 16 edges per block (4 per wave) -> 4096 blocks.
  dots_kernel<<<EE / 16, 256, 0, stream>>>(edge_attr, edge_vector, dots);

  // Kernel 2: N*N/4 threads, 4 pairs per thread.
  const int total_threads = (NN * NN) / 4;  // 1,048,576
  pairs_kernel<<<total_threads / 256, 256, 0, stream>>>(ept, dots, out);
}